// Round 5
// baseline (266.166 us; speedup 1.0000x reference)
//
#include <hip/hip_runtime.h>

#define TT 24
#define DM 128
#define DI 256
#define NTOK 207
#define EPSV 1e-5f
#define NSEQ 828
#define NROWS (NSEQ * TT)  // 19872

typedef unsigned short u16;
typedef unsigned int u32;

__device__ __forceinline__ float rlane(float v, int l) {
  return __int_as_float(__builtin_amdgcn_readlane(__float_as_int(v), l));
}
__device__ __forceinline__ float fsilu(float x) { return x * (1.f / (1.f + __expf(-x))); }
__device__ __forceinline__ float fsoftplus(float x) {
  return (x > 15.f) ? x : 0.69314718f * log2f(1.f + exp2f(1.44269504f * x));
}
__device__ __forceinline__ u16 f2b(float f) {  // RNE bf16
  u32 u = __float_as_uint(f);
  u += 0x7fffu + ((u >> 16) & 1u);
  return (u16)(u >> 16);
}
__device__ __forceinline__ float b2f(u16 h) { return __uint_as_float(((u32)h) << 16); }
__device__ __forceinline__ u32 pkmul(u32 a, u32 b) {  // elementwise bf16x2 product
  const float p0 = __uint_as_float(a << 16) * __uint_as_float(b << 16);
  const float p1 = __uint_as_float(a & 0xffff0000u) * __uint_as_float(b & 0xffff0000u);
  return ((u32)f2b(p0)) | (((u32)f2b(p1)) << 16);
}

// ===================== k1: LN1 + in_proj (row-parallel GEMM) =====================
// 16 rows/block; out: xx (c<256) and silu(z) (c>=256) as bf16 in ws.
__global__ __launch_bounds__(256) void k1_ln_inproj(
    const float* __restrict__ x, const float* __restrict__ g1,
    const float* __restrict__ b1, const float* __restrict__ wt_in,
    u16* __restrict__ xx_g, u16* __restrict__ zz_g) {
  __shared__ __align__(16) u16 h_l[16 * DM];
  const int tid = threadIdx.x, lane = tid & 63, wv = tid >> 6;
  const int r0 = blockIdx.x * 16;
#pragma unroll
  for (int i = 0; i < 4; ++i) {
    const int rl = wv * 4 + i, g = r0 + rl;
    const int bn = g / TT, t = g - bn * TT;
    const int b = bn / NTOK, n = bn - b * NTOK;
    const float* xr = x + (((size_t)(b * TT + t)) * NTOK + n) * DM;
    const float v0 = xr[lane], v1 = xr[lane + 64];
    float s1 = v0 + v1, s2 = v0 * v0 + v1 * v1;
#pragma unroll
    for (int off = 32; off; off >>= 1) {
      s1 += __shfl_xor(s1, off, 64);
      s2 += __shfl_xor(s2, off, 64);
    }
    const float m = s1 * (1.f / DM);
    const float r = rsqrtf(s2 * (1.f / DM) - m * m + EPSV);
    h_l[rl * DM + lane] = f2b((v0 - m) * r * g1[lane] + b1[lane]);
    h_l[rl * DM + lane + 64] = f2b((v1 - m) * r * g1[lane + 64] + b1[lane + 64]);
  }
  __syncthreads();
  // GEMM: thread = 4 cols x 8 rows; K=128 in bf16 pairs (broadcast LDS reads)
  const int cidx = tid & 127, rg = tid >> 7;
  const int c0 = cidx * 4;
  float acc[8][4];
#pragma unroll
  for (int r = 0; r < 8; ++r)
#pragma unroll
    for (int c = 0; c < 4; ++c) acc[r][c] = 0.f;
#pragma unroll 4
  for (int kk = 0; kk < 64; ++kk) {
    const float4 w0 = *(const float4*)(wt_in + (2 * kk) * 512 + c0);
    const float4 w1 = *(const float4*)(wt_in + (2 * kk + 1) * 512 + c0);
#pragma unroll
    for (int r = 0; r < 8; ++r) {
      const u32 hv = *(const u32*)(h_l + (rg * 8 + r) * DM + 2 * kk);
      const float e0 = __uint_as_float(hv << 16);
      const float e1 = __uint_as_float(hv & 0xffff0000u);
      acc[r][0] = fmaf(e0, w0.x, acc[r][0]); acc[r][0] = fmaf(e1, w1.x, acc[r][0]);
      acc[r][1] = fmaf(e0, w0.y, acc[r][1]); acc[r][1] = fmaf(e1, w1.y, acc[r][1]);
      acc[r][2] = fmaf(e0, w0.z, acc[r][2]); acc[r][2] = fmaf(e1, w1.z, acc[r][2]);
      acc[r][3] = fmaf(e0, w0.w, acc[r][3]); acc[r][3] = fmaf(e1, w1.w, acc[r][3]);
    }
  }
  const bool isz = (c0 >= 256);
#pragma unroll
  for (int r = 0; r < 8; ++r) {
    const int g = r0 + rg * 8 + r;
    float a0 = acc[r][0], a1 = acc[r][1], a2 = acc[r][2], a3 = acc[r][3];
    if (isz) { a0 = fsilu(a0); a1 = fsilu(a1); a2 = fsilu(a2); a3 = fsilu(a3); }
    ushort4 o;
    o.x = f2b(a0); o.y = f2b(a1); o.z = f2b(a2); o.w = f2b(a3);
    if (isz)
      *(ushort4*)(zz_g + (size_t)g * DI + (c0 - 256)) = o;
    else
      *(ushort4*)(xx_g + (size_t)g * DI + c0) = o;
  }
}

// ===================== k2: conv + x_proj + scan (both branches) =====================
template <bool REV>
__device__ __forceinline__ void branch2(
    const float* __restrict__ cw, const float* __restrict__ cb,
    const float* __restrict__ xw, const float* __restrict__ dw,
    const float* __restrict__ db, const float* __restrict__ Al,
    const float* __restrict__ Dp, const u16* __restrict__ xx_l,
    u16* __restrict__ xc_l, u16* __restrict__ y_l, float* __restrict__ xd,
    int tid, int lane) {
  // depthwise causal conv (channel-local; REV = re-indexed read)
  {
    float cwr[4];
#pragma unroll
    for (int k = 0; k < 4; ++k) cwr[k] = cw[tid * 4 + k];
    const float cbd = cb[tid];
    float xm3 = 0.f, xm2 = 0.f, xm1 = 0.f;
#pragma unroll 4
    for (int t = 0; t < TT; ++t) {
      const float xt = b2f(xx_l[(REV ? (TT - 1 - t) : t) * DI + tid]);
      float acc = fmaf(cwr[0], xm3, cbd);
      acc = fmaf(cwr[1], xm2, acc);
      acc = fmaf(cwr[2], xm1, acc);
      acc = fmaf(cwr[3], xt, acc);
      xc_l[t * DI + tid] = f2b(fsilu(acc));
      xm3 = xm2; xm2 = xm1; xm1 = xt;
    }
  }
  __syncthreads();

  // x_dbl: e-pairs x 8-way K split; jx rotation avoids bank conflicts
  if (tid < 160) {
    const int pe = tid >> 3, q = tid & 7;
    const float* w0 = xw + (2 * pe) * DI;
    const float* w1 = w0 + DI;
    const int rot = (q >> 1) & 3;
#pragma unroll
    for (int c = 0; c < 4; ++c) {
      float a0[6], a1[6];
#pragma unroll
      for (int i = 0; i < 6; ++i) { a0[i] = 0.f; a1[i] = 0.f; }
#pragma unroll
      for (int jj = 0; jj < 4; ++jj) {
        const int jx = jj ^ rot;
        const int dbase = q * 32 + jx * 8;
        const float4 wa0 = *(const float4*)(w0 + dbase);
        const float4 wb0 = *(const float4*)(w0 + dbase + 4);
        const float4 wa1 = *(const float4*)(w1 + dbase);
        const float4 wb1 = *(const float4*)(w1 + dbase + 4);
#pragma unroll
        for (int i = 0; i < 6; ++i) {
          const uint4 vv = *(const uint4*)(xc_l + (c * 6 + i) * DI + dbase);
          const float e0 = __uint_as_float(vv.x << 16);
          const float e1 = __uint_as_float(vv.x & 0xffff0000u);
          const float e2 = __uint_as_float(vv.y << 16);
          const float e3 = __uint_as_float(vv.y & 0xffff0000u);
          const float e4 = __uint_as_float(vv.z << 16);
          const float e5 = __uint_as_float(vv.z & 0xffff0000u);
          const float e6 = __uint_as_float(vv.w << 16);
          const float e7 = __uint_as_float(vv.w & 0xffff0000u);
          a0[i] = fmaf(e0, wa0.x, a0[i]); a0[i] = fmaf(e1, wa0.y, a0[i]);
          a0[i] = fmaf(e2, wa0.z, a0[i]); a0[i] = fmaf(e3, wa0.w, a0[i]);
          a0[i] = fmaf(e4, wb0.x, a0[i]); a0[i] = fmaf(e5, wb0.y, a0[i]);
          a0[i] = fmaf(e6, wb0.z, a0[i]); a0[i] = fmaf(e7, wb0.w, a0[i]);
          a1[i] = fmaf(e0, wa1.x, a1[i]); a1[i] = fmaf(e1, wa1.y, a1[i]);
          a1[i] = fmaf(e2, wa1.z, a1[i]); a1[i] = fmaf(e3, wa1.w, a1[i]);
          a1[i] = fmaf(e4, wb1.x, a1[i]); a1[i] = fmaf(e5, wb1.y, a1[i]);
          a1[i] = fmaf(e6, wb1.z, a1[i]); a1[i] = fmaf(e7, wb1.w, a1[i]);
        }
      }
#pragma unroll
      for (int i = 0; i < 6; ++i) {
        float v0 = a0[i], v1 = a1[i];
        v0 += __shfl_xor(v0, 1, 64); v0 += __shfl_xor(v0, 2, 64); v0 += __shfl_xor(v0, 4, 64);
        v1 += __shfl_xor(v1, 1, 64); v1 += __shfl_xor(v1, 2, 64); v1 += __shfl_xor(v1, 4, 64);
        if (q == 0) {
          xd[(c * 6 + i) * 40 + 2 * pe] = v0;
          xd[(c * 6 + i) * 40 + 2 * pe + 1] = v1;
        }
      }
    }
  }
  __syncthreads();

  // selective scan; broadcast via readlane; y accumulated bf16 in LDS
  {
    float dwr[8];
#pragma unroll
    for (int r = 0; r < 8; ++r) dwr[r] = dw[tid * 8 + r];
    const float dbd = db[tid], Dpd = Dp[tid];
    float aa[16];
#pragma unroll
    for (int s = 0; s < 16; ++s) aa[s] = -__expf(Al[tid * 16 + s]) * 1.44269504f;
    float hst[16];
#pragma unroll
    for (int s = 0; s < 16; ++s) hst[s] = 0.f;
#pragma unroll 4
    for (int t = 0; t < TT; ++t) {
      const float bc0 = xd[t * 40 + (lane & 31)];
      const float bc1 = xd[t * 40 + 32 + (lane & 7)];
      float dtraw = dbd;
#pragma unroll
      for (int r = 0; r < 8; ++r) dtraw = fmaf(rlane(bc0, r), dwr[r], dtraw);
      const float dt = fsoftplus(dtraw);
      const float u = b2f(xc_l[t * DI + tid]);
      const float dtu = dt * u;
      float yt = 0.f;
#pragma unroll
      for (int s = 0; s < 16; ++s) {
        const float Bs = rlane(bc0, 8 + s);
        const float Cs = (s < 8) ? rlane(bc0, 24 + s) : rlane(bc1, s - 8);
        const float ef = exp2f(dt * aa[s]);
        hst[s] = fmaf(hst[s], ef, dtu * Bs);
        yt = fmaf(hst[s], Cs, yt);
      }
      yt = fmaf(Dpd, u, yt);
      const int ti = REV ? (TT - 1 - t) : t;
      if (REV)
        y_l[ti * DI + tid] = f2b(b2f(y_l[ti * DI + tid]) + yt);
      else
        y_l[ti * DI + tid] = f2b(yt);
    }
  }
  __syncthreads();
}

__global__ __launch_bounds__(256) void k2_scan(
    const float* __restrict__ cwf, const float* __restrict__ cbf,
    const float* __restrict__ xwf, const float* __restrict__ dwf,
    const float* __restrict__ dbf, const float* __restrict__ Alf,
    const float* __restrict__ Dpf, const float* __restrict__ cwb,
    const float* __restrict__ cbb, const float* __restrict__ xwb,
    const float* __restrict__ dwb, const float* __restrict__ dbb,
    const float* __restrict__ Alb, const float* __restrict__ Dpb,
    const u16* __restrict__ xx_g, u16* __restrict__ zz_g) {
  __shared__ __align__(16) u16 xx_l[TT * DI];  // 12 KB
  __shared__ __align__(16) u16 xc_l[TT * DI];  // 12 KB
  __shared__ __align__(16) u16 y_l[TT * DI];   // 12 KB
  __shared__ __align__(16) float xd[TT * 40];  // 3.75 KB  -> 40.7 KB total: 4 blocks/CU
  const int tid = threadIdx.x, lane = tid & 63;
  const int sq = blockIdx.x;
  // stage xx once (used forward + reversed)
  {
    const uint4* src = (const uint4*)(xx_g + (size_t)sq * TT * DI);
    uint4* dst = (uint4*)xx_l;
#pragma unroll
    for (int i = 0; i < 3; ++i) dst[tid + i * 256] = src[tid + i * 256];
  }
  __syncthreads();
  branch2<false>(cwf, cbf, xwf, dwf, dbf, Alf, Dpf, xx_l, xc_l, y_l, xd, tid, lane);
  branch2<true>(cwb, cbb, xwb, dwb, dbb, Alb, Dpb, xx_l, xc_l, y_l, xd, tid, lane);
  // ysz = (y_f + y_b_rev) * silu(z); overwrite zz in place (k1 rewrites it each call)
  u16* zrow = zz_g + (size_t)sq * TT * DI;
#pragma unroll
  for (int i = 0; i < 3; ++i) {
    const int idx = tid + i * 256;
    const uint4 yv = ((const uint4*)y_l)[idx];
    const uint4 zv = ((const uint4*)zrow)[idx];
    uint4 o;
    o.x = pkmul(yv.x, zv.x); o.y = pkmul(yv.y, zv.y);
    o.z = pkmul(yv.z, zv.z); o.w = pkmul(yv.w, zv.w);
    ((uint4*)zrow)[idx] = o;
  }
}

// ===================== k3: out_proj + LN2 + residual =====================
__global__ __launch_bounds__(256) void k3_outproj(
    const float* __restrict__ x, const float* __restrict__ wt_out,
    const u16* __restrict__ zz_g, const float* __restrict__ g2,
    const float* __restrict__ b2, float* __restrict__ out) {
  __shared__ __align__(16) u16 ys_l[16 * DI];   // 8 KB
  __shared__ __align__(16) float o_l[16 * DM];  // 8 KB
  const int tid = threadIdx.x, lane = tid & 63, wv = tid >> 6;
  const int r0 = blockIdx.x * 16;
  {
    const uint4* src = (const uint4*)(zz_g + (size_t)r0 * DI);
    uint4* dst = (uint4*)ys_l;
    dst[tid] = src[tid];
    dst[tid + 256] = src[tid + 256];
  }
  __syncthreads();
  // GEMM: thread = 2 cols x 4 rows, K=256
  const int cidx = tid & 63, rg = tid >> 6;
  const int c0 = cidx * 2;
  float acc[4][2];
#pragma unroll
  for (int r = 0; r < 4; ++r) { acc[r][0] = 0.f; acc[r][1] = 0.f; }
#pragma unroll 4
  for (int kk = 0; kk < 128; ++kk) {
    const float2 w0 = *(const float2*)(wt_out + (2 * kk) * DM + c0);
    const float2 w1 = *(const float2*)(wt_out + (2 * kk + 1) * DM + c0);
#pragma unroll
    for (int r = 0; r < 4; ++r) {
      const u32 hv = *(const u32*)(ys_l + (rg * 4 + r) * DI + 2 * kk);
      const float e0 = __uint_as_float(hv << 16);
      const float e1 = __uint_as_float(hv & 0xffff0000u);
      acc[r][0] = fmaf(e0, w0.x, acc[r][0]); acc[r][0] = fmaf(e1, w1.x, acc[r][0]);
      acc[r][1] = fmaf(e0, w0.y, acc[r][1]); acc[r][1] = fmaf(e1, w1.y, acc[r][1]);
    }
  }
#pragma unroll
  for (int r = 0; r < 4; ++r) {
    o_l[(rg * 4 + r) * DM + c0] = acc[r][0];
    o_l[(rg * 4 + r) * DM + c0 + 1] = acc[r][1];
  }
  __syncthreads();
#pragma unroll
  for (int i = 0; i < 4; ++i) {
    const int rl = wv * 4 + i, g = r0 + rl;
    const int bn = g / TT, t = g - bn * TT;
    const int b = bn / NTOK, n = bn - b * NTOK;
    const float o0 = o_l[rl * DM + lane], o1 = o_l[rl * DM + lane + 64];
    float s1 = o0 + o1, s2 = o0 * o0 + o1 * o1;
#pragma unroll
    for (int off = 32; off; off >>= 1) {
      s1 += __shfl_xor(s1, off, 64);
      s2 += __shfl_xor(s2, off, 64);
    }
    const float m = s1 * (1.f / DM);
    const float r = rsqrtf(s2 * (1.f / DM) - m * m + EPSV);
    const float* xr = x + (((size_t)(b * TT + t)) * NTOK + n) * DM;
    float* orow = out + (((size_t)(b * TT + t)) * NTOK + n) * DM;
    orow[lane] = (o0 - m) * r * g2[lane] + b2[lane] + xr[lane];
    orow[lane + 64] = (o1 - m) * r * g2[lane + 64] + b2[lane + 64] + xr[lane + 64];
  }
}

// one-shot weight transpose into workspace
__global__ void transpose_w(const float* __restrict__ Wi, const float* __restrict__ Wo,
                            float* __restrict__ wt) {
  const int i = blockIdx.x * 256 + threadIdx.x;
  if (i < 512 * 128) {  // Wt_in [128][512] <- Win [512][128]
    const int r = i & 511, c = i >> 9;
    wt[i] = Wi[r * 128 + c];
  }
  if (i < 256 * 128) {  // Wt_out [256][128] <- Wout [128][256]
    const int d = i >> 7, r = i & 127;
    wt[512 * 128 + i] = Wo[r * 256 + d];
  }
}

// ===================== fallback: round-3 monolithic (no workspace) =====================
template <bool SIL>
__device__ __forceinline__ void gemm_h(const float* __restrict__ W,
                                       const float* __restrict__ h_s,
                                       u16* __restrict__ bufp, int tid) {
  const int cg = tid & 31, tg = tid >> 5;
  const int c0 = cg * 8, t0 = tg * 3;
  float acc[3][8];
#pragma unroll
  for (int a = 0; a < 3; ++a)
#pragma unroll
    for (int b = 0; b < 8; ++b) acc[a][b] = 0.f;
  const float4* h4 = (const float4*)h_s;
#pragma unroll 4
  for (int j = 0; j < 32; ++j) {
    float4 hv[3];
#pragma unroll
    for (int a = 0; a < 3; ++a) hv[a] = h4[(t0 + a) * 32 + j];
#pragma unroll
    for (int b = 0; b < 8; ++b) {
      float4 w = *(const float4*)(W + (c0 + b) * DM + j * 4);
#pragma unroll
      for (int a = 0; a < 3; ++a) {
        acc[a][b] = fmaf(hv[a].x, w.x, acc[a][b]);
        acc[a][b] = fmaf(hv[a].y, w.y, acc[a][b]);
        acc[a][b] = fmaf(hv[a].z, w.z, acc[a][b]);
        acc[a][b] = fmaf(hv[a].w, w.w, acc[a][b]);
      }
    }
  }
#pragma unroll
  for (int a = 0; a < 3; ++a) {
    ushort4 o0, o1;
    float v;
    v = SIL ? fsilu(acc[a][0]) : acc[a][0]; o0.x = f2b(v);
    v = SIL ? fsilu(acc[a][1]) : acc[a][1]; o0.y = f2b(v);
    v = SIL ? fsilu(acc[a][2]) : acc[a][2]; o0.z = f2b(v);
    v = SIL ? fsilu(acc[a][3]) : acc[a][3]; o0.w = f2b(v);
    v = SIL ? fsilu(acc[a][4]) : acc[a][4]; o1.x = f2b(v);
    v = SIL ? fsilu(acc[a][5]) : acc[a][5]; o1.y = f2b(v);
    v = SIL ? fsilu(acc[a][6]) : acc[a][6]; o1.z = f2b(v);
    v = SIL ? fsilu(acc[a][7]) : acc[a][7]; o1.w = f2b(v);
    *(ushort4*)(bufp + (t0 + a) * DI + c0) = o0;
    *(ushort4*)(bufp + (t0 + a) * DI + c0 + 4) = o1;
  }
}

template <bool REV>
__device__ __forceinline__ void run_branch_m(
    const float* __restrict__ cw, const float* __restrict__ cb,
    const float* __restrict__ xw, const float* __restrict__ dw,
    const float* __restrict__ db, const float* __restrict__ Al,
    const float* __restrict__ Dp, const u16* __restrict__ xx_s,
    u16* __restrict__ xc_s, const u16* __restrict__ sz_s,
    float* __restrict__ y_s, float* __restrict__ xd, int tid, int lane) {
  {
    float cwr[4];
#pragma unroll
    for (int k = 0; k < 4; ++k) cwr[k] = cw[tid * 4 + k];
    const float cbd = cb[tid];
    float xm3 = 0.f, xm2 = 0.f, xm1 = 0.f;
#pragma unroll 4
    for (int t = 0; t < TT; ++t) {
      const float xt = b2f(xx_s[(REV ? (TT - 1 - t) : t) * DI + tid]);
      float acc = fmaf(cwr[0], xm3, cbd);
      acc = fmaf(cwr[1], xm2, acc);
      acc = fmaf(cwr[2], xm1, acc);
      acc = fmaf(cwr[3], xt, acc);
      xc_s[t * DI + tid] = f2b(fsilu(acc));
      xm3 = xm2; xm2 = xm1; xm1 = xt;
    }
  }
  __syncthreads();
  if (tid < 160) {
    const int pe = tid >> 3, q = tid & 7;
    const float* w0 = xw + (2 * pe) * DI;
    const float* w1 = w0 + DI;
    const int rot = (q >> 1) & 3;
#pragma unroll
    for (int c = 0; c < 4; ++c) {
      float a0[6], a1[6];
#pragma unroll
      for (int i = 0; i < 6; ++i) { a0[i] = 0.f; a1[i] = 0.f; }
#pragma unroll
      for (int jj = 0; jj < 4; ++jj) {
        const int jx = jj ^ rot;
        const int dbase = q * 32 + jx * 8;
        const float4 wa0 = *(const float4*)(w0 + dbase);
        const float4 wb0 = *(const float4*)(w0 + dbase + 4);
        const float4 wa1 = *(const float4*)(w1 + dbase);
        const float4 wb1 = *(const float4*)(w1 + dbase + 4);
#pragma unroll
        for (int i = 0; i < 6; ++i) {
          const uint4 vv = *(const uint4*)(xc_s + (c * 6 + i) * DI + dbase);
          const float e0 = __uint_as_float(vv.x << 16);
          const float e1 = __uint_as_float(vv.x & 0xffff0000u);
          const float e2 = __uint_as_float(vv.y << 16);
          const float e3 = __uint_as_float(vv.y & 0xffff0000u);
          const float e4 = __uint_as_float(vv.z << 16);
          const float e5 = __uint_as_float(vv.z & 0xffff0000u);
          const float e6 = __uint_as_float(vv.w << 16);
          const float e7 = __uint_as_float(vv.w & 0xffff0000u);
          a0[i] = fmaf(e0, wa0.x, a0[i]); a0[i] = fmaf(e1, wa0.y, a0[i]);
          a0[i] = fmaf(e2, wa0.z, a0[i]); a0[i] = fmaf(e3, wa0.w, a0[i]);
          a0[i] = fmaf(e4, wb0.x, a0[i]); a0[i] = fmaf(e5, wb0.y, a0[i]);
          a0[i] = fmaf(e6, wb0.z, a0[i]); a0[i] = fmaf(e7, wb0.w, a0[i]);
          a1[i] = fmaf(e0, wa1.x, a1[i]); a1[i] = fmaf(e1, wa1.y, a1[i]);
          a1[i] = fmaf(e2, wa1.z, a1[i]); a1[i] = fmaf(e3, wa1.w, a1[i]);
          a1[i] = fmaf(e4, wb1.x, a1[i]); a1[i] = fmaf(e5, wb1.y, a1[i]);
          a1[i] = fmaf(e6, wb1.z, a1[i]); a1[i] = fmaf(e7, wb1.w, a1[i]);
        }
      }
#pragma unroll
      for (int i = 0; i < 6; ++i) {
        float v0 = a0[i], v1 = a1[i];
        v0 += __shfl_xor(v0, 1, 64); v0 += __shfl_xor(v0, 2, 64); v0 += __shfl_xor(v0, 4, 64);
        v1 += __shfl_xor(v1, 1, 64); v1 += __shfl_xor(v1, 2, 64); v1 += __shfl_xor(v1, 4, 64);
        if (q == 0) {
          xd[(c * 6 + i) * 40 + 2 * pe] = v0;
          xd[(c * 6 + i) * 40 + 2 * pe + 1] = v1;
        }
      }
    }
  }
  __syncthreads();
  {
    float dwr[8];
#pragma unroll
    for (int r = 0; r < 8; ++r) dwr[r] = dw[tid * 8 + r];
    const float dbd = db[tid], Dpd = Dp[tid];
    float aa[16];
#pragma unroll
    for (int s = 0; s < 16; ++s) aa[s] = -__expf(Al[tid * 16 + s]) * 1.44269504f;
    float hst[16];
#pragma unroll
    for (int s = 0; s < 16; ++s) hst[s] = 0.f;
#pragma unroll 4
    for (int t = 0; t < TT; ++t) {
      const float bc0 = xd[t * 40 + (lane & 31)];
      const float bc1 = xd[t * 40 + 32 + (lane & 7)];
      float dtraw = dbd;
#pragma unroll
      for (int r = 0; r < 8; ++r) dtraw = fmaf(rlane(bc0, r), dwr[r], dtraw);
      const float dt = fsoftplus(dtraw);
      const float u = b2f(xc_s[t * DI + tid]);
      const float dtu = dt * u;
      float yt = 0.f;
#pragma unroll
      for (int s = 0; s < 16; ++s) {
        const float Bs = rlane(bc0, 8 + s);
        const float Cs = (s < 8) ? rlane(bc0, 24 + s) : rlane(bc1, s - 8);
        const float ef = exp2f(dt * aa[s]);
        hst[s] = fmaf(hst[s], ef, dtu * Bs);
        yt = fmaf(hst[s], Cs, yt);
      }
      yt = fmaf(Dpd, u, yt);
      const int ti = REV ? (TT - 1 - t) : t;
      if (REV)
        y_s[ti * DI + tid] = (y_s[ti * DI + tid] + yt) * b2f(sz_s[ti * DI + tid]);
      else
        y_s[ti * DI + tid] = yt;
    }
  }
  __syncthreads();
}

__global__ __launch_bounds__(256) void bimamba_mono(
    const float* __restrict__ x, const float* __restrict__ g1,
    const float* __restrict__ b1, const float* __restrict__ Win,
    const float* __restrict__ cwf, const float* __restrict__ cbf,
    const float* __restrict__ xwf, const float* __restrict__ dwf,
    const float* __restrict__ dbf, const float* __restrict__ Alf,
    const float* __restrict__ Dpf, const float* __restrict__ cwb,
    const float* __restrict__ cbb, const float* __restrict__ xwb,
    const float* __restrict__ dwb, const float* __restrict__ dbb,
    const float* __restrict__ Alb, const float* __restrict__ Dpb,
    const float* __restrict__ Wout, const float* __restrict__ g2,
    const float* __restrict__ b2, float* __restrict__ out) {
  __shared__ __align__(16) float h_s[TT * DM];
  __shared__ __align__(16) u16 xx_s[TT * DI];
  __shared__ __align__(16) u16 xc_s[TT * DI];
  __shared__ __align__(16) u16 sz_s[TT * DI];
  __shared__ __align__(16) float y_s[TT * DI];

  const int tid = threadIdx.x;
  const int lane = tid & 63, wv = tid >> 6;
  const int sq = blockIdx.x;
  const int bb = sq / NTOK, nn = sq % NTOK;
  const float* xbase = x + ((size_t)bb * TT * NTOK + nn) * DM;

#pragma unroll
  for (int i = 0; i < 6; ++i) {
    const int t = wv + 4 * i;
    const float* xr = xbase + (size_t)t * NTOK * DM;
    const float v0 = xr[lane], v1 = xr[lane + 64];
    float s1 = v0 + v1, s2 = v0 * v0 + v1 * v1;
#pragma unroll
    for (int off = 32; off; off >>= 1) {
      s1 += __shfl_xor(s1, off, 64);
      s2 += __shfl_xor(s2, off, 64);
    }
    const float m = s1 * (1.f / DM);
    const float r = rsqrtf(s2 * (1.f / DM) - m * m + EPSV);
    h_s[t * DM + lane] = (v0 - m) * r * g1[lane] + b1[lane];
    h_s[t * DM + lane + 64] = (v1 - m) * r * g1[lane + 64] + b1[lane + 64];
  }
  __syncthreads();

  gemm_h<true>(Win + DI * DM, h_s, sz_s, tid);
  gemm_h<false>(Win, h_s, xx_s, tid);
  __syncthreads();

  float* xd = h_s;
  run_branch_m<false>(cwf, cbf, xwf, dwf, dbf, Alf, Dpf, xx_s, xc_s, sz_s, y_s, xd, tid, lane);
  run_branch_m<true>(cwb, cbb, xwb, dwb, dbb, Alb, Dpb, xx_s, xc_s, sz_s, y_s, xd, tid, lane);

  {
    const int cg = tid & 15, tg = (tid >> 4) & 7, kh = tid >> 7;
    const int c0 = cg * 8, t0 = tg * 3;
    float acc[3][8];
#pragma unroll
    for (int a = 0; a < 3; ++a)
#pragma unroll
      for (int b = 0; b < 8; ++b) acc[a][b] = 0.f;
    const float4* y4 = (const float4*)y_s;
#pragma unroll 4
    for (int j = 0; j < 32; ++j) {
      float4 yv[3];
#pragma unroll
      for (int a = 0; a < 3; ++a) yv[a] = y4[(t0 + a) * 64 + kh * 32 + j];
#pragma unroll
      for (int b = 0; b < 8; ++b) {
        float4 w = *(const float4*)(Wout + (c0 + b) * DI + kh * 128 + j * 4);
#pragma unroll
        for (int a = 0; a < 3; ++a) {
          acc[a][b] = fmaf(yv[a].x, w.x, acc[a][b]);
          acc[a][b] = fmaf(yv[a].y, w.y, acc[a][b]);
          acc[a][b] = fmaf(yv[a].z, w.z, acc[a][b]);
          acc[a][b] = fmaf(yv[a].w, w.w, acc[a][b]);
        }
      }
    }
    if (kh) {
#pragma unroll
      for (int a = 0; a < 3; ++a) {
        float4* dst = (float4*)(h_s + (t0 + a) * DM + c0);
        dst[0] = make_float4(acc[a][0], acc[a][1], acc[a][2], acc[a][3]);
        dst[1] = make_float4(acc[a][4], acc[a][5], acc[a][6], acc[a][7]);
      }
    }
    __syncthreads();
    if (!kh) {
#pragma unroll
      for (int a = 0; a < 3; ++a)
#pragma unroll
        for (int b = 0; b < 8; ++b) h_s[(t0 + a) * DM + c0 + b] += acc[a][b];
    }
  }
  __syncthreads();

#pragma unroll
  for (int i = 0; i < 6; ++i) {
    const int t = wv + 4 * i;
    const float o0 = h_s[t * DM + lane], o1 = h_s[t * DM + lane + 64];
    float s1 = o0 + o1, s2 = o0 * o0 + o1 * o1;
#pragma unroll
    for (int off = 32; off; off >>= 1) {
      s1 += __shfl_xor(s1, off, 64);
      s2 += __shfl_xor(s2, off, 64);
    }
    const float m = s1 * (1.f / DM);
    const float r = rsqrtf(s2 * (1.f / DM) - m * m + EPSV);
    const float* xr = xbase + (size_t)t * NTOK * DM;
    float* orow = out + (((size_t)bb * TT + t) * NTOK + nn) * DM;
    orow[lane] = (o0 - m) * r * g2[lane] + b2[lane] + xr[lane];
    orow[lane + 64] = (o1 - m) * r * g2[lane + 64] + b2[lane + 64] + xr[lane + 64];
  }
}

// ws layout (bytes): [0, 262144) Wt_in | [262144, 393216) Wt_out |
// [393216, +10174464) xx bf16 | [10567680, +10174464) zz bf16  -> total 20742144
#define WS_XX_OFF 393216
#define WS_ZZ_OFF 10567680
#define WS_NEEDED 20742144

extern "C" void kernel_launch(void* const* d_in, const int* in_sizes, int n_in,
                              void* d_out, int out_size, void* d_ws, size_t ws_size,
                              hipStream_t stream) {
  const float* x = (const float*)d_in[0];
  if (ws_size >= (size_t)WS_NEEDED) {
    float* wt = (float*)d_ws;
    u16* xx_g = (u16*)((char*)d_ws + WS_XX_OFF);
    u16* zz_g = (u16*)((char*)d_ws + WS_ZZ_OFF);
    transpose_w<<<dim3(256), dim3(256), 0, stream>>>(
        (const float*)d_in[3], (const float*)d_in[18], wt);
    k1_ln_inproj<<<dim3(NROWS / 16), dim3(256), 0, stream>>>(
        x, (const float*)d_in[1], (const float*)d_in[2], wt, xx_g, zz_g);
    k2_scan<<<dim3(NSEQ), dim3(256), 0, stream>>>(
        (const float*)d_in[4], (const float*)d_in[5], (const float*)d_in[6],
        (const float*)d_in[7], (const float*)d_in[8], (const float*)d_in[9],
        (const float*)d_in[10], (const float*)d_in[11], (const float*)d_in[12],
        (const float*)d_in[13], (const float*)d_in[14], (const float*)d_in[15],
        (const float*)d_in[16], (const float*)d_in[17], xx_g, zz_g);
    k3_outproj<<<dim3(NROWS / 16), dim3(256), 0, stream>>>(
        x, wt + 512 * 128, zz_g, (const float*)d_in[19], (const float*)d_in[20],
        (float*)d_out);
  } else {
    bimamba_mono<<<dim3(NSEQ), dim3(256), 0, stream>>>(
        x, (const float*)d_in[1], (const float*)d_in[2], (const float*)d_in[3],
        (const float*)d_in[4], (const float*)d_in[5], (const float*)d_in[6],
        (const float*)d_in[7], (const float*)d_in[8], (const float*)d_in[9],
        (const float*)d_in[10], (const float*)d_in[11], (const float*)d_in[12],
        (const float*)d_in[13], (const float*)d_in[14], (const float*)d_in[15],
        (const float*)d_in[16], (const float*)d_in[17], (const float*)d_in[18],
        (const float*)d_in[19], (const float*)d_in[20], (float*)d_out);
  }
}